// Round 1
// baseline (1466.187 us; speedup 1.0000x reference)
//
#include <hip/hip_runtime.h>
#include <hip/hip_bf16.h>
#include <math.h>

#define T_SEQ 256
#define FEAT  128
#define UNITS 50
#define NG    200   // 4*UNITS
#define OUTD  74
#define BATCH 1024

// ---------------------------------------------------------------------------
// Phase A: z[b][ti][j] = x[b][t0+ti][:] @ W[:,j]   (no bias; bias added in rec)
// Tile: 64 rows x 200 cols (full N), K-chunks of 32. 320 threads, 8x5/thread.
// blockIdx.y selects direction (0=fwd uses W_f -> zf, 1=bwd uses W_b -> zb).
// ---------------------------------------------------------------------------
__global__ __launch_bounds__(320) void proj_kernel(
    const float* __restrict__ x,
    const float* __restrict__ Wf, const float* __restrict__ Wb,
    float* __restrict__ zf, float* __restrict__ zb,
    int Tc, int lTc, int t0f, int t0b)
{
    __shared__ float smem[12800];                 // 51.2 KB, reused for epilogue
    float (*As)[68] = (float (*)[68])smem;        // [32][68] transposed A (pad 68 keeps 16B align)
    float* Bs = smem + 32 * 68;                   // [32][200]

    const int tid = threadIdx.x;
    const int dir = blockIdx.y;
    const float* W = dir ? Wb : Wf;
    float* z = dir ? zb : zf;
    const int t0 = dir ? t0b : t0f;
    const int m0 = blockIdx.x * 64;
    const int tn = tid % 40;                      // 40 col-groups of 5
    const int tm = tid / 40;                      // 8 row-groups of 8

    float acc[8][5];
#pragma unroll
    for (int i = 0; i < 8; ++i)
#pragma unroll
        for (int j = 0; j < 5; ++j) acc[i][j] = 0.f;

    for (int kc = 0; kc < 4; ++kc) {
        const int k0 = kc * 32;
        __syncthreads();
        // ---- stage A tile (64 rows x 32 k), transposed into As[k][row]
#pragma unroll
        for (int it = 0; it < 2; ++it) {
            int idx = tid + it * 320;
            if (idx < 512) {
                int i  = idx >> 3;
                int k4 = idx & 7;
                int r  = m0 + i;
                int b  = r >> lTc;
                int ti = r & (Tc - 1);
                const float4 v = *(const float4*)(x + ((size_t)b * T_SEQ + (t0 + ti)) * FEAT + k0 + k4 * 4);
                As[k4 * 4 + 0][i] = v.x;
                As[k4 * 4 + 1][i] = v.y;
                As[k4 * 4 + 2][i] = v.z;
                As[k4 * 4 + 3][i] = v.w;
            }
        }
        // ---- stage B tile (32 k x 200 cols)
#pragma unroll
        for (int it = 0; it < 5; ++it) {
            int idx = tid + it * 320;             // < 1600 exactly
            int k   = idx / 50;
            int j4  = idx % 50;
            *(float4*)(Bs + k * NG + j4 * 4) = *(const float4*)(W + (size_t)(k0 + k) * NG + j4 * 4);
        }
        __syncthreads();
        // ---- compute
#pragma unroll
        for (int k = 0; k < 32; ++k) {
            const float4 a0 = *(const float4*)&As[k][tm * 8];
            const float4 a1 = *(const float4*)&As[k][tm * 8 + 4];
            float bv[5];
#pragma unroll
            for (int j = 0; j < 5; ++j) bv[j] = Bs[k * NG + tn * 5 + j];
            const float av[8] = {a0.x, a0.y, a0.z, a0.w, a1.x, a1.y, a1.z, a1.w};
#pragma unroll
            for (int i = 0; i < 8; ++i)
#pragma unroll
                for (int j = 0; j < 5; ++j) acc[i][j] = fmaf(av[i], bv[j], acc[i][j]);
        }
    }
    __syncthreads();
    // ---- epilogue: stage to LDS, then coalesced float4 stores
    float* Cs = smem;                             // [64][200]
#pragma unroll
    for (int i = 0; i < 8; ++i)
#pragma unroll
        for (int j = 0; j < 5; ++j)
            Cs[(tm * 8 + i) * NG + tn * 5 + j] = acc[i][j];
    __syncthreads();
#pragma unroll
    for (int it = 0; it < 10; ++it) {
        int idx = tid + it * 320;                 // < 3200 exactly
        int row = idx / 50;
        int j4  = idx % 50;
        int r   = m0 + row;
        int b   = r >> lTc;
        int ti  = r & (Tc - 1);
        *(float4*)(z + ((size_t)b * Tc + ti) * NG + j4 * 4) = *(const float4*)(Cs + row * NG + j4 * 4);
    }
}

// ---------------------------------------------------------------------------
// Phase B: recurrence. 512 threads = 2 batch rows x 256 lanes (200 active).
// Thread (r, j<200) owns gate column j: U column in registers, h broadcast
// from LDS. Unit threads (j<50) own c and produce h. 2 barriers per step.
// ---------------------------------------------------------------------------
__global__ __launch_bounds__(512) void rec_kernel(
    const float* __restrict__ zf, const float* __restrict__ zb,
    const float* __restrict__ Uf, const float* __restrict__ Ub,
    const float* __restrict__ bf_, const float* __restrict__ bb_,
    float* __restrict__ hF, float* __restrict__ cF,
    float* __restrict__ hB, float* __restrict__ cB,
    int Tc, int first)
{
    const int tid = threadIdx.x;
    const int r   = tid >> 8;                     // 0..1 (row within block)
    const int cu  = tid & 255;
    const int dir = blockIdx.y;
    const float* z    = dir ? zb : zf;
    const float* U    = dir ? Ub : Uf;
    const float* bias = dir ? bb_ : bf_;
    float* hS = dir ? hB : hF;
    float* cS = dir ? cB : cF;
    const int b = blockIdx.x * 2 + r;

    __shared__ float h_sh[2][52];                 // padded to 52 (16B align, zero pad)
    __shared__ float g_sh[2][NG];

    const int  j   = cu;
    const bool act = (cu < NG);

    float Ureg[52];
#pragma unroll
    for (int k = 0; k < 52; ++k) Ureg[k] = 0.f;
    if (act) {
#pragma unroll
        for (int k = 0; k < 50; ++k) Ureg[k] = U[k * NG + j];
    }
    const float bj = act ? bias[j] : 0.f;

    float c = 0.f;
    if (cu < 50 && !first) c = cS[b * 50 + cu];
    if (cu < 52) h_sh[r][cu] = (!first && cu < 50) ? hS[b * 50 + cu] : 0.f;
    __syncthreads();

    const int fwd  = (dir == 0);
    int ti         = fwd ? 0 : Tc - 1;
    const int step = fwd ? 1 : -1;
    const size_t zbase = (size_t)b * Tc * NG + j;

    float zc = act ? z[zbase + (size_t)ti * NG] : 0.f;

    for (int tt = 0; tt < Tc; ++tt) {
        const int tin = ti + step;
        float zn = 0.f;
        if (tt + 1 < Tc && act) zn = z[zbase + (size_t)tin * NG];   // prefetch next step

        float acc = zc + bj;
#pragma unroll
        for (int k4 = 0; k4 < 13; ++k4) {
            const float4 h4 = *(const float4*)&h_sh[r][k4 * 4];     // wave-uniform -> broadcast
            acc = fmaf(h4.x, Ureg[k4 * 4 + 0], acc);
            acc = fmaf(h4.y, Ureg[k4 * 4 + 1], acc);
            acc = fmaf(h4.z, Ureg[k4 * 4 + 2], acc);
            acc = fmaf(h4.w, Ureg[k4 * 4 + 3], acc);
        }
        if (act) g_sh[r][j] = acc;
        __syncthreads();
        if (cu < 50) {
            float gi = g_sh[r][cu];
            float gf = g_sh[r][50 + cu];
            float gg = g_sh[r][100 + cu];
            float go = g_sh[r][150 + cu];
            gi = 1.f / (1.f + expf(-gi));
            gf = 1.f / (1.f + expf(-gf));
            gg = fmaxf(gg, 0.f);                  // cell activation = relu
            go = 1.f / (1.f + expf(-go));
            c  = gf * c + gi * gg;
            h_sh[r][cu] = go * fmaxf(c, 0.f);     // h = o * relu(c)
        }
        __syncthreads();
        zc = zn;
        ti = tin;
    }
    if (cu < 50) {
        hS[b * 50 + cu] = h_sh[r][cu];
        cS[b * 50 + cu] = c;
    }
}

// ---------------------------------------------------------------------------
// Phase C: logits = [h_f, h_b] @ W_d + b_d ; softmax. One block per batch row.
// ---------------------------------------------------------------------------
__global__ __launch_bounds__(128) void head_kernel(
    const float* __restrict__ hF, const float* __restrict__ hB,
    const float* __restrict__ Wd, const float* __restrict__ bd,
    float* __restrict__ out)
{
    const int b   = blockIdx.x;
    const int tid = threadIdx.x;
    __shared__ float hsh[100];
    __shared__ float red[128];

    if (tid < 50) {
        hsh[tid]      = hF[b * 50 + tid];
        hsh[50 + tid] = hB[b * 50 + tid];
    }
    __syncthreads();

    float logit = -INFINITY;
    if (tid < OUTD) {
        float acc = bd[tid];
#pragma unroll 4
        for (int k = 0; k < 100; ++k) acc = fmaf(hsh[k], Wd[k * OUTD + tid], acc);
        logit = acc;
    }
    red[tid] = logit;
    __syncthreads();
    for (int s = 64; s > 0; s >>= 1) {
        if (tid < s) red[tid] = fmaxf(red[tid], red[tid + s]);
        __syncthreads();
    }
    const float m = red[0];
    __syncthreads();
    const float e = (tid < OUTD) ? expf(logit - m) : 0.f;
    red[tid] = e;
    __syncthreads();
    for (int s = 64; s > 0; s >>= 1) {
        if (tid < s) red[tid] += red[tid + s];
        __syncthreads();
    }
    if (tid < OUTD) out[b * OUTD + tid] = e / red[0];
}

// ---------------------------------------------------------------------------
extern "C" void kernel_launch(void* const* d_in, const int* in_sizes, int n_in,
                              void* d_out, int out_size, void* d_ws, size_t ws_size,
                              hipStream_t stream)
{
    const float* x  = (const float*)d_in[0];
    const float* Wf = (const float*)d_in[1];
    const float* Uf = (const float*)d_in[2];
    const float* bf = (const float*)d_in[3];
    const float* Wb = (const float*)d_in[4];
    const float* Ub = (const float*)d_in[5];
    const float* bb = (const float*)d_in[6];
    const float* Wd = (const float*)d_in[7];
    const float* bd = (const float*)d_in[8];
    float* out = (float*)d_out;

    // Pick largest time-chunk Tc whose z buffers + state fit in workspace.
    const size_t state_bytes = 4ull * BATCH * UNITS * 4;   // hF,cF,hB,cB
    int Tc = T_SEQ;
    while (Tc > 1 && (2ull * BATCH * (size_t)Tc * NG * 4 + state_bytes) > ws_size) Tc >>= 1;
    const int lTc = __builtin_ctz((unsigned)Tc);

    const size_t SZ = (size_t)BATCH * Tc * NG * 4;
    float* zf = (float*)d_ws;
    float* zb = (float*)((char*)d_ws + SZ);
    float* st = (float*)((char*)d_ws + 2 * SZ);
    float* hF = st;
    float* cF = st + BATCH * UNITS;
    float* hB = st + 2 * BATCH * UNITS;
    float* cB = st + 3 * BATCH * UNITS;

    const int nc = T_SEQ / Tc;
    for (int c = 0; c < nc; ++c) {
        const int t0f = c * Tc;
        const int t0b = T_SEQ - (c + 1) * Tc;     // bwd dir consumes time in reverse
        proj_kernel<<<dim3(BATCH * Tc / 64, 2), 320, 0, stream>>>(
            x, Wf, Wb, zf, zb, Tc, lTc, t0f, t0b);
        rec_kernel<<<dim3(BATCH / 2, 2), 512, 0, stream>>>(
            zf, zb, Uf, Ub, bf, bb, hF, cF, hB, cB, Tc, c == 0);
    }
    head_kernel<<<BATCH, 128, 0, stream>>>(hF, hB, Wd, bd, out);
}

// Round 5
// 1378.108 us; speedup vs baseline: 1.0639x; 1.0639x over previous
//
#include <hip/hip_runtime.h>
#include <hip/hip_bf16.h>
#include <math.h>

#define T_SEQ 256
#define FEAT  128
#define UNITS 50
#define NG    200   // 4*UNITS
#define OUTD  74
#define BATCH 1024
#define NPAD  224   // 7 strips of 32
#define WPLANE (NPAD * FEAT)   // 28672 elements per Wt plane

typedef __attribute__((ext_vector_type(8)))  short bf16x8;
typedef __attribute__((ext_vector_type(16))) float f32x16;

__device__ __forceinline__ unsigned short f2bf(float f) {
    unsigned u = __float_as_uint(f);
    return (unsigned short)((u + 0x7fffu + ((u >> 16) & 1u)) >> 16);
}
__device__ __forceinline__ float bf2f(unsigned short h) {
    return __uint_as_float(((unsigned)h) << 16);
}
__device__ __forceinline__ float sigf(float x) {
    return __builtin_amdgcn_rcpf(1.f + __expf(-x));
}

// ---------------------------------------------------------------------------
// Prep: W[128][200] -> W^T hi/lo bf16 [224 cols][128 k], zero-padded cols.
// Planes: 0=F_hi 1=F_lo 2=B_hi 3=B_lo
// ---------------------------------------------------------------------------
__global__ __launch_bounds__(256) void prep_w(
    const float* __restrict__ Wf, const float* __restrict__ Wb,
    unsigned short* __restrict__ Wt)
{
    const int idx = blockIdx.x * 256 + threadIdx.x;     // < 28672
    const int dir = blockIdx.y;
    const int col = idx >> 7, k = idx & 127;
    const float* W = dir ? Wb : Wf;
    const float v = (col < NG) ? W[k * NG + col] : 0.f;
    const unsigned short hi = f2bf(v);
    const unsigned short lo = f2bf(v - bf2f(hi));
    Wt[(size_t)(dir * 2 + 0) * WPLANE + idx] = hi;
    Wt[(size_t)(dir * 2 + 1) * WPLANE + idx] = lo;
}

// ---------------------------------------------------------------------------
// Prep: window of x -> bf16 hi/lo, layout [B*Tc][128] matching proj M order.
// ---------------------------------------------------------------------------
__global__ __launch_bounds__(256) void prep_x(
    const float* __restrict__ x,
    unsigned short* __restrict__ xh, unsigned short* __restrict__ xl,
    int Tc, int lTc, int t0, int n4)
{
    const int stride = gridDim.x * blockDim.x;
    for (int e4 = blockIdx.x * blockDim.x + threadIdx.x; e4 < n4; e4 += stride) {
        const int row = e4 >> 5, k4 = e4 & 31;
        const int b = row >> lTc, ti = row & (Tc - 1);
        const float4 v = *(const float4*)(x + (((size_t)(b * T_SEQ + t0 + ti)) << 7) + (k4 << 2));
        ushort4 hi, lo;
        hi.x = f2bf(v.x); lo.x = f2bf(v.x - bf2f(hi.x));
        hi.y = f2bf(v.y); lo.y = f2bf(v.y - bf2f(hi.y));
        hi.z = f2bf(v.z); lo.z = f2bf(v.z - bf2f(hi.z));
        hi.w = f2bf(v.w); lo.w = f2bf(v.w - bf2f(hi.w));
        *(ushort4*)(xh + ((size_t)e4 << 2)) = hi;
        *(ushort4*)(xl + ((size_t)e4 << 2)) = lo;
    }
}

// ---------------------------------------------------------------------------
// Projection GEMM via bf16x3 split MFMA: z[M=B*Tc][200] = X[M][128] @ W[128][200]
// Block = 7 waves (448 thr). Wave w owns col strip [w*32, w*32+32).
// B-frags (W^T hi/lo) resident in regs; A-frags global-loaded with prefetch.
// mfma_f32_32x32x16_bf16: A lane: row=l&31, k=8*(l>>5)+j; B lane: col=l&31,
// k=8*(l>>5)+j; D lane: col=l&31, row=(r&3)+8*(r>>2)+4*(l>>5).
// ---------------------------------------------------------------------------
__global__ __launch_bounds__(448, 2) void proj_mfma(
    const unsigned short* __restrict__ xfh, const unsigned short* __restrict__ xfl,
    const unsigned short* __restrict__ xbh, const unsigned short* __restrict__ xbl,
    const unsigned short* __restrict__ Wt,
    float* __restrict__ zf, float* __restrict__ zb,
    int mpb, int nMT)
{
    const int dir = blockIdx.y;
    const unsigned short* __restrict__ Ah_p = dir ? xbh : xfh;
    const unsigned short* __restrict__ Al_p = dir ? xbl : xfl;
    float* __restrict__ z = dir ? zb : zf;
    const unsigned short* __restrict__ Wth = Wt + (size_t)(dir * 2) * WPLANE;
    const unsigned short* __restrict__ Wtl = Wth + WPLANE;

    const int l    = threadIdx.x & 63;
    const int wv   = threadIdx.x >> 6;       // 0..6 strip
    const int ln   = l & 31;
    const int half = l >> 5;
    const int col  = wv * 32 + ln;

    bf16x8 Bh[8], Bl[8];
#pragma unroll
    for (int ks = 0; ks < 8; ++ks) {
        const size_t wo = (size_t)col * 128 + ks * 16 + half * 8;
        Bh[ks] = *(const bf16x8*)(Wth + wo);
        Bl[ks] = *(const bf16x8*)(Wtl + wo);
    }
    const bool colOK = (col < NG);

    int mt = blockIdx.x * mpb;
    bf16x8 Ah[8], Al[8], Ah2[8], Al2[8];
    {
        const size_t ab = ((size_t)(mt * 32 + ln)) << 7;
#pragma unroll
        for (int ks = 0; ks < 8; ++ks) {
            Ah[ks] = *(const bf16x8*)(Ah_p + ab + ks * 16 + half * 8);
            Al[ks] = *(const bf16x8*)(Al_p + ab + ks * 16 + half * 8);
        }
    }

    for (int i = 0; i < mpb; ++i) {
        // prefetch next tile's A frags
        const int mtn = (i + 1 < mpb) ? (mt + 1) : mt;
        const size_t an = ((size_t)(mtn * 32 + ln)) << 7;
#pragma unroll
        for (int ks = 0; ks < 8; ++ks) {
            Ah2[ks] = *(const bf16x8*)(Ah_p + an + ks * 16 + half * 8);
            Al2[ks] = *(const bf16x8*)(Al_p + an + ks * 16 + half * 8);
        }

        f32x16 acc = {};
#pragma unroll
        for (int ks = 0; ks < 8; ++ks) {
            acc = __builtin_amdgcn_mfma_f32_32x32x16_bf16(Ah[ks], Bh[ks], acc, 0, 0, 0);
            acc = __builtin_amdgcn_mfma_f32_32x32x16_bf16(Ah[ks], Bl[ks], acc, 0, 0, 0);
            acc = __builtin_amdgcn_mfma_f32_32x32x16_bf16(Al[ks], Bh[ks], acc, 0, 0, 0);
        }

        if (colOK) {
            float* zp = z + (size_t)(mt * 32 + half * 4) * NG + col;
#pragma unroll
            for (int r = 0; r < 16; ++r) {
                const int row = (r & 3) + ((r >> 2) << 3);
                zp[(size_t)row * NG] = acc[r];
            }
        }
#pragma unroll
        for (int ks = 0; ks < 8; ++ks) { Ah[ks] = Ah2[ks]; Al[ks] = Al2[ks]; }
        ++mt;
    }
}

// ---------------------------------------------------------------------------
// Recurrence: one 64-lane wave per (batch row, dir). Lane u (<50) owns unit u:
// U columns for all 4 gates in registers (200 VGPR). h broadcast via LDS,
// single cheap 1-wave barrier per step. z prefetched one step ahead.
// ---------------------------------------------------------------------------
__global__ __launch_bounds__(64, 2) void rec2(
    const float* __restrict__ zf, const float* __restrict__ zb,
    const float* __restrict__ Uf, const float* __restrict__ Ub,
    const float* __restrict__ bf_, const float* __restrict__ bb_,
    float* __restrict__ hF, float* __restrict__ cF,
    float* __restrict__ hB, float* __restrict__ cB,
    int Tc, int first)
{
    const int u = threadIdx.x;
    const int b = blockIdx.x, dir = blockIdx.y;
    const float* __restrict__ z    = dir ? zb : zf;
    const float* __restrict__ U    = dir ? Ub : Uf;
    const float* __restrict__ bias = dir ? bb_ : bf_;
    float* __restrict__ hS = dir ? hB : hF;
    float* __restrict__ cS = dir ? cB : cF;
    const bool act = (u < UNITS);

    float Ur[4][50];
#pragma unroll
    for (int k = 0; k < 50; ++k)
#pragma unroll
        for (int g = 0; g < 4; ++g)
            Ur[g][k] = act ? U[k * NG + g * 50 + u] : 0.f;

    float bj[4];
#pragma unroll
    for (int g = 0; g < 4; ++g) bj[g] = act ? bias[g * 50 + u] : 0.f;

    float c = (act && !first) ? cS[b * 50 + u] : 0.f;

    __shared__ __align__(16) float hsh[52];
    if (u < 52) hsh[u] = (u < 50 && !first) ? hS[b * 50 + u] : 0.f;
    __syncthreads();

    const int stp = dir ? -1 : 1;
    int ti = dir ? (Tc - 1) : 0;
    const float* __restrict__ zr = z + (size_t)b * Tc * NG;

    float zc[4] = {0.f, 0.f, 0.f, 0.f};
    if (act) {
#pragma unroll
        for (int g = 0; g < 4; ++g) zc[g] = zr[(size_t)ti * NG + g * 50 + u];
    }

    for (int tt = 0; tt < Tc; ++tt) {
        const int tin = ti + stp;
        float zn[4] = {0.f, 0.f, 0.f, 0.f};
        if (tt + 1 < Tc && act) {
#pragma unroll
            for (int g = 0; g < 4; ++g) zn[g] = zr[(size_t)tin * NG + g * 50 + u];
        }

        float a0 = zc[0] + bj[0], a1 = zc[1] + bj[1];
        float a2 = zc[2] + bj[2], a3 = zc[3] + bj[3];
#pragma unroll
        for (int k4 = 0; k4 < 12; ++k4) {
            const float4 h4 = *(const float4*)(hsh + (k4 << 2));
            a0 = fmaf(h4.x, Ur[0][k4 * 4 + 0], a0);
            a1 = fmaf(h4.x, Ur[1][k4 * 4 + 0], a1);
            a2 = fmaf(h4.x, Ur[2][k4 * 4 + 0], a2);
            a3 = fmaf(h4.x, Ur[3][k4 * 4 + 0], a3);
            a0 = fmaf(h4.y, Ur[0][k4 * 4 + 1], a0);
            a1 = fmaf(h4.y, Ur[1][k4 * 4 + 1], a1);
            a2 = fmaf(h4.y, Ur[2][k4 * 4 + 1], a2);
            a3 = fmaf(h4.y, Ur[3][k4 * 4 + 1], a3);
            a0 = fmaf(h4.z, Ur[0][k4 * 4 + 2], a0);
            a1 = fmaf(h4.z, Ur[1][k4 * 4 + 2], a1);
            a2 = fmaf(h4.z, Ur[2][k4 * 4 + 2], a2);
            a3 = fmaf(h4.z, Ur[3][k4 * 4 + 2], a3);
            a0 = fmaf(h4.w, Ur[0][k4 * 4 + 3], a0);
            a1 = fmaf(h4.w, Ur[1][k4 * 4 + 3], a1);
            a2 = fmaf(h4.w, Ur[2][k4 * 4 + 3], a2);
            a3 = fmaf(h4.w, Ur[3][k4 * 4 + 3], a3);
        }
        {
            const float2 h2 = *(const float2*)(hsh + 48);
            a0 = fmaf(h2.x, Ur[0][48], a0); a1 = fmaf(h2.x, Ur[1][48], a1);
            a2 = fmaf(h2.x, Ur[2][48], a2); a3 = fmaf(h2.x, Ur[3][48], a3);
            a0 = fmaf(h2.y, Ur[0][49], a0); a1 = fmaf(h2.y, Ur[1][49], a1);
            a2 = fmaf(h2.y, Ur[2][49], a2); a3 = fmaf(h2.y, Ur[3][49], a3);
        }

        const float si = sigf(a0);
        const float sf2 = sigf(a1);
        const float gg = fmaxf(a2, 0.f);
        const float so = sigf(a3);
        c = fmaf(sf2, c, si * gg);
        const float h = so * fmaxf(c, 0.f);

        if (act) hsh[u] = h;
        __syncthreads();
        zc[0] = zn[0]; zc[1] = zn[1]; zc[2] = zn[2]; zc[3] = zn[3];
        ti = tin;
    }

    if (act) {
        hS[b * 50 + u] = hsh[u];
        cS[b * 50 + u] = c;
    }
}

// ---------------------------------------------------------------------------
// Head: logits = [h_f, h_b] @ W_d + b_d ; softmax. One block per batch row.
// ---------------------------------------------------------------------------
__global__ __launch_bounds__(128) void head_kernel(
    const float* __restrict__ hF, const float* __restrict__ hB,
    const float* __restrict__ Wd, const float* __restrict__ bd,
    float* __restrict__ out)
{
    const int b   = blockIdx.x;
    const int tid = threadIdx.x;
    __shared__ float hsh[100];
    __shared__ float red[128];

    if (tid < 50) {
        hsh[tid]      = hF[b * 50 + tid];
        hsh[50 + tid] = hB[b * 50 + tid];
    }
    __syncthreads();

    float logit = -INFINITY;
    if (tid < OUTD) {
        float acc = bd[tid];
#pragma unroll 4
        for (int k = 0; k < 100; ++k) acc = fmaf(hsh[k], Wd[k * OUTD + tid], acc);
        logit = acc;
    }
    red[tid] = logit;
    __syncthreads();
    for (int s = 64; s > 0; s >>= 1) {
        if (tid < s) red[tid] = fmaxf(red[tid], red[tid + s]);
        __syncthreads();
    }
    const float m = red[0];
    __syncthreads();
    const float e = (tid < OUTD) ? expf(logit - m) : 0.f;
    red[tid] = e;
    __syncthreads();
    for (int s = 64; s > 0; s >>= 1) {
        if (tid < s) red[tid] += red[tid + s];
        __syncthreads();
    }
    if (tid < OUTD) out[b * OUTD + tid] = e / red[0];
}

// ---------------------------------------------------------------------------
extern "C" void kernel_launch(void* const* d_in, const int* in_sizes, int n_in,
                              void* d_out, int out_size, void* d_ws, size_t ws_size,
                              hipStream_t stream)
{
    const float* x  = (const float*)d_in[0];
    const float* Wf = (const float*)d_in[1];
    const float* Uf = (const float*)d_in[2];
    const float* bf = (const float*)d_in[3];
    const float* Wb = (const float*)d_in[4];
    const float* Ub = (const float*)d_in[5];
    const float* bb = (const float*)d_in[6];
    const float* Wd = (const float*)d_in[7];
    const float* bd = (const float*)d_in[8];
    float* out = (float*)d_out;

    auto aln = [](size_t v) { return (v + 255) & ~(size_t)255; };

    // choose largest time chunk that fits in workspace
    int Tc = T_SEQ;
    bool shx = true;
    for (;;) {
        shx = (Tc == T_SEQ);
        const size_t zsz = aln((size_t)BATCH * Tc * NG * 4);
        const size_t xsz = aln((size_t)BATCH * Tc * FEAT * 2);
        const size_t need = 2 * zsz + (shx ? 2 : 4) * xsz
                          + aln(4 * WPLANE * 2) + aln(4ull * BATCH * UNITS * 4);
        if (need <= ws_size || Tc == 8) break;
        Tc >>= 1;
    }
    const int lTc = __builtin_ctz((unsigned)Tc);
    const size_t zsz = aln((size_t)BATCH * Tc * NG * 4);
    const size_t xsz = aln((size_t)BATCH * Tc * FEAT * 2);

    char* p = (char*)d_ws;
    float* zf = (float*)p; p += zsz;
    float* zb = (float*)p; p += zsz;
    unsigned short* xfh = (unsigned short*)p; p += xsz;
    unsigned short* xfl = (unsigned short*)p; p += xsz;
    unsigned short* xbh = xfh;
    unsigned short* xbl = xfl;
    if (!shx) {
        xbh = (unsigned short*)p; p += xsz;
        xbl = (unsigned short*)p; p += xsz;
    }
    unsigned short* Wt = (unsigned short*)p; p += aln(4 * WPLANE * 2);
    float* st = (float*)p;
    float* hF = st;
    float* cF = st + BATCH * UNITS;
    float* hB = st + 2 * BATCH * UNITS;
    float* cB = st + 3 * BATCH * UNITS;

    prep_w<<<dim3(WPLANE / 256, 2), 256, 0, stream>>>(Wf, Wb, Wt);

    const int n4  = BATCH * Tc * 32;          // float4 groups per x window
    const int nMT = BATCH * Tc / 32;          // 32-row M-tiles
    const int NBLK = (nMT < 512) ? nMT : 512;
    const int mpb = nMT / NBLK;
    const int nc  = T_SEQ / Tc;

    for (int c = 0; c < nc; ++c) {
        const int t0f = c * Tc;
        const int t0b = T_SEQ - (c + 1) * Tc;
        prep_x<<<2048, 256, 0, stream>>>(x, xfh, xfl, Tc, lTc, t0f, n4);
        if (!shx)
            prep_x<<<2048, 256, 0, stream>>>(x, xbh, xbl, Tc, lTc, t0b, n4);
        proj_mfma<<<dim3(NBLK, 2), 448, 0, stream>>>(
            xfh, xfl, xbh, xbl, Wt, zf, zb, mpb, nMT);
        rec2<<<dim3(BATCH, 2), 64, 0, stream>>>(
            zf, zb, Uf, Ub, bf, bb, hF, cF, hB, cB, Tc, c == 0);
    }
    head_kernel<<<BATCH, 128, 0, stream>>>(hF, hB, Wd, bd, out);
}

// Round 6
// 945.377 us; speedup vs baseline: 1.5509x; 1.4577x over previous
//
#include <hip/hip_runtime.h>
#include <hip/hip_bf16.h>
#include <math.h>

#define T_SEQ 256
#define FEAT  128
#define UNITS 50
#define NG    200   // 4*UNITS
#define OUTD  74
#define BATCH 1024
#define NPAD  224   // 7 strips of 32
#define WPLANE (NPAD * FEAT)   // 28672 elements per Wt plane

typedef __attribute__((ext_vector_type(8)))  short bf16x8;
typedef __attribute__((ext_vector_type(16))) float f32x16;

__device__ __forceinline__ unsigned short f2bf(float f) {
    unsigned u = __float_as_uint(f);
    return (unsigned short)((u + 0x7fffu + ((u >> 16) & 1u)) >> 16);
}
__device__ __forceinline__ float bf2f(unsigned short h) {
    return __uint_as_float(((unsigned)h) << 16);
}
__device__ __forceinline__ float sigf(float x) {
    return __builtin_amdgcn_rcpf(1.f + __expf(-x));
}

// ---------------------------------------------------------------------------
// Prep: W[128][200] -> W^T hi/lo bf16 [224 cols][128 k], zero-padded cols.
// Planes: 0=F_hi 1=F_lo 2=B_hi 3=B_lo
// ---------------------------------------------------------------------------
__global__ __launch_bounds__(256) void prep_w(
    const float* __restrict__ Wf, const float* __restrict__ Wb,
    unsigned short* __restrict__ Wt)
{
    const int idx = blockIdx.x * 256 + threadIdx.x;     // < 28672
    const int dir = blockIdx.y;
    const int col = idx >> 7, k = idx & 127;
    const float* W = dir ? Wb : Wf;
    const float v = (col < NG) ? W[k * NG + col] : 0.f;
    const unsigned short hi = f2bf(v);
    const unsigned short lo = f2bf(v - bf2f(hi));
    Wt[(size_t)(dir * 2 + 0) * WPLANE + idx] = hi;
    Wt[(size_t)(dir * 2 + 1) * WPLANE + idx] = lo;
}

// ---------------------------------------------------------------------------
// Prep: window of x -> bf16 hi/lo, layout [B*Tc][128] matching proj M order.
// ---------------------------------------------------------------------------
__global__ __launch_bounds__(256) void prep_x(
    const float* __restrict__ x,
    unsigned short* __restrict__ xh, unsigned short* __restrict__ xl,
    int Tc, int lTc, int t0, int n4)
{
    const int stride = gridDim.x * blockDim.x;
    for (int e4 = blockIdx.x * blockDim.x + threadIdx.x; e4 < n4; e4 += stride) {
        const int row = e4 >> 5, k4 = e4 & 31;
        const int b = row >> lTc, ti = row & (Tc - 1);
        const float4 v = *(const float4*)(x + (((size_t)(b * T_SEQ + t0 + ti)) << 7) + (k4 << 2));
        ushort4 hi, lo;
        hi.x = f2bf(v.x); lo.x = f2bf(v.x - bf2f(hi.x));
        hi.y = f2bf(v.y); lo.y = f2bf(v.y - bf2f(hi.y));
        hi.z = f2bf(v.z); lo.z = f2bf(v.z - bf2f(hi.z));
        hi.w = f2bf(v.w); lo.w = f2bf(v.w - bf2f(hi.w));
        *(ushort4*)(xh + ((size_t)e4 << 2)) = hi;
        *(ushort4*)(xl + ((size_t)e4 << 2)) = lo;
    }
}

// ---------------------------------------------------------------------------
// Projection GEMM via bf16x3 split MFMA: z[M=B*Tc][200] = X[M][128] @ W[128][200]
// Block = 7 waves (448 thr). Wave w owns col strip [w*32, w*32+32).
// B-frags (W^T hi/lo) resident in regs; A-frags global-loaded with prefetch.
// mfma_f32_32x32x16_bf16: A lane: row=l&31, k=8*(l>>5)+j; B lane: col=l&31,
// k=8*(l>>5)+j; D lane: col=l&31, row=(r&3)+8*(r>>2)+4*(l>>5).
// ---------------------------------------------------------------------------
__global__ __launch_bounds__(448, 2) void proj_mfma(
    const unsigned short* __restrict__ xfh, const unsigned short* __restrict__ xfl,
    const unsigned short* __restrict__ xbh, const unsigned short* __restrict__ xbl,
    const unsigned short* __restrict__ Wt,
    float* __restrict__ zf, float* __restrict__ zb,
    int mpb, int nMT)
{
    const int dir = blockIdx.y;
    const unsigned short* __restrict__ Ah_p = dir ? xbh : xfh;
    const unsigned short* __restrict__ Al_p = dir ? xbl : xfl;
    float* __restrict__ z = dir ? zb : zf;
    const unsigned short* __restrict__ Wth = Wt + (size_t)(dir * 2) * WPLANE;
    const unsigned short* __restrict__ Wtl = Wth + WPLANE;

    const int l    = threadIdx.x & 63;
    const int wv   = threadIdx.x >> 6;       // 0..6 strip
    const int ln   = l & 31;
    const int half = l >> 5;
    const int col  = wv * 32 + ln;

    bf16x8 Bh[8], Bl[8];
#pragma unroll
    for (int ks = 0; ks < 8; ++ks) {
        const size_t wo = (size_t)col * 128 + ks * 16 + half * 8;
        Bh[ks] = *(const bf16x8*)(Wth + wo);
        Bl[ks] = *(const bf16x8*)(Wtl + wo);
    }
    const bool colOK = (col < NG);

    int mt = blockIdx.x * mpb;
    bf16x8 Ah[8], Al[8], Ah2[8], Al2[8];
    {
        const size_t ab = ((size_t)(mt * 32 + ln)) << 7;
#pragma unroll
        for (int ks = 0; ks < 8; ++ks) {
            Ah[ks] = *(const bf16x8*)(Ah_p + ab + ks * 16 + half * 8);
            Al[ks] = *(const bf16x8*)(Al_p + ab + ks * 16 + half * 8);
        }
    }

    for (int i = 0; i < mpb; ++i) {
        // prefetch next tile's A frags
        const int mtn = (i + 1 < mpb) ? (mt + 1) : mt;
        const size_t an = ((size_t)(mtn * 32 + ln)) << 7;
#pragma unroll
        for (int ks = 0; ks < 8; ++ks) {
            Ah2[ks] = *(const bf16x8*)(Ah_p + an + ks * 16 + half * 8);
            Al2[ks] = *(const bf16x8*)(Al_p + an + ks * 16 + half * 8);
        }

        f32x16 acc = {};
#pragma unroll
        for (int ks = 0; ks < 8; ++ks) {
            acc = __builtin_amdgcn_mfma_f32_32x32x16_bf16(Ah[ks], Bh[ks], acc, 0, 0, 0);
            acc = __builtin_amdgcn_mfma_f32_32x32x16_bf16(Ah[ks], Bl[ks], acc, 0, 0, 0);
            acc = __builtin_amdgcn_mfma_f32_32x32x16_bf16(Al[ks], Bh[ks], acc, 0, 0, 0);
        }

        if (colOK) {
            float* zp = z + (size_t)(mt * 32 + half * 4) * NG + col;
#pragma unroll
            for (int r = 0; r < 16; ++r) {
                const int row = (r & 3) + ((r >> 2) << 3);
                zp[(size_t)row * NG] = acc[r];
            }
        }
#pragma unroll
        for (int ks = 0; ks < 8; ++ks) { Ah[ks] = Ah2[ks]; Al[ks] = Al2[ks]; }
        ++mt;
    }
}

// ---------------------------------------------------------------------------
// Recurrence v3: one 256-thread block per (batch row, dir). Lane j<200 owns
// ONE gate column: U column (50 floats) in registers -> no spill (rec2 had
// Ur[200] -> spilled at VGPR_Count=128 -> scratch-bound at 6.1us/step).
// Lane j computes its gate pre-activation + activation; lanes <50 do the
// c/h update. h broadcast via LDS float4 (wave-uniform -> bank broadcast).
// ---------------------------------------------------------------------------
__global__ __launch_bounds__(256) void rec3(
    const float* __restrict__ zf, const float* __restrict__ zb,
    const float* __restrict__ Uf, const float* __restrict__ Ub,
    const float* __restrict__ bf_, const float* __restrict__ bb_,
    float* __restrict__ hF, float* __restrict__ cF,
    float* __restrict__ hB, float* __restrict__ cB,
    int Tc, int first)
{
    const int j = threadIdx.x;
    const int b = blockIdx.x, dir = blockIdx.y;
    const float* __restrict__ z    = dir ? zb : zf;
    const float* __restrict__ U    = dir ? Ub : Uf;
    const float* __restrict__ bias = dir ? bb_ : bf_;
    float* __restrict__ hS = dir ? hB : hF;
    float* __restrict__ cS = dir ? cB : cF;
    const bool act = (j < NG);
    const bool isg = (j >= 100) && (j < 150);   // g-gate columns use relu

    float Ur[50];
#pragma unroll
    for (int k = 0; k < 50; ++k) Ur[k] = act ? U[k * NG + j] : 0.f;
    const float bj = act ? bias[j] : 0.f;

    __shared__ __align__(16) float hsh[52];
    __shared__ float gsh[NG];

    float c = 0.f;
    if (j < 50) {
        c      = first ? 0.f : cS[b * 50 + j];
        hsh[j] = first ? 0.f : hS[b * 50 + j];
    }
    if (j >= 50 && j < 52) hsh[j] = 0.f;
    __syncthreads();

    const int stp = dir ? -1 : 1;
    int ti = dir ? (Tc - 1) : 0;
    const float* __restrict__ zr = z + (size_t)b * Tc * NG;

    float zc = act ? zr[(size_t)ti * NG + j] : 0.f;

    for (int tt = 0; tt < Tc; ++tt) {
        const int tin = ti + stp;
        float zn = 0.f;
        if (tt + 1 < Tc && act) zn = zr[(size_t)tin * NG + j];  // prefetch

        float a = zc + bj;
#pragma unroll
        for (int k4 = 0; k4 < 12; ++k4) {
            const float4 h4 = *(const float4*)(hsh + (k4 << 2));  // broadcast
            a = fmaf(h4.x, Ur[k4 * 4 + 0], a);
            a = fmaf(h4.y, Ur[k4 * 4 + 1], a);
            a = fmaf(h4.z, Ur[k4 * 4 + 2], a);
            a = fmaf(h4.w, Ur[k4 * 4 + 3], a);
        }
        {
            const float2 h2 = *(const float2*)(hsh + 48);
            a = fmaf(h2.x, Ur[48], a);
            a = fmaf(h2.y, Ur[49], a);
        }

        const float s = sigf(a);
        const float r = fmaxf(a, 0.f);
        if (act) gsh[j] = isg ? r : s;
        __syncthreads();

        if (j < 50) {
            const float gi = gsh[j];
            const float gf = gsh[50 + j];
            const float gg = gsh[100 + j];
            const float go = gsh[150 + j];
            c = fmaf(gf, c, gi * gg);
            hsh[j] = go * fmaxf(c, 0.f);
        }
        __syncthreads();

        zc = zn;
        ti = tin;
    }

    if (j < 50) {
        hS[b * 50 + j] = hsh[j];
        cS[b * 50 + j] = c;
    }
}

// ---------------------------------------------------------------------------
// Head: logits = [h_f, h_b] @ W_d + b_d ; softmax. One block per batch row.
// ---------------------------------------------------------------------------
__global__ __launch_bounds__(128) void head_kernel(
    const float* __restrict__ hF, const float* __restrict__ hB,
    const float* __restrict__ Wd, const float* __restrict__ bd,
    float* __restrict__ out)
{
    const int b   = blockIdx.x;
    const int tid = threadIdx.x;
    __shared__ float hsh[100];
    __shared__ float red[128];

    if (tid < 50) {
        hsh[tid]      = hF[b * 50 + tid];
        hsh[50 + tid] = hB[b * 50 + tid];
    }
    __syncthreads();

    float logit = -INFINITY;
    if (tid < OUTD) {
        float acc = bd[tid];
#pragma unroll 4
        for (int k = 0; k < 100; ++k) acc = fmaf(hsh[k], Wd[k * OUTD + tid], acc);
        logit = acc;
    }
    red[tid] = logit;
    __syncthreads();
    for (int s = 64; s > 0; s >>= 1) {
        if (tid < s) red[tid] = fmaxf(red[tid], red[tid + s]);
        __syncthreads();
    }
    const float m = red[0];
    __syncthreads();
    const float e = (tid < OUTD) ? expf(logit - m) : 0.f;
    red[tid] = e;
    __syncthreads();
    for (int s = 64; s > 0; s >>= 1) {
        if (tid < s) red[tid] += red[tid + s];
        __syncthreads();
    }
    if (tid < OUTD) out[b * OUTD + tid] = e / red[0];
}

// ---------------------------------------------------------------------------
extern "C" void kernel_launch(void* const* d_in, const int* in_sizes, int n_in,
                              void* d_out, int out_size, void* d_ws, size_t ws_size,
                              hipStream_t stream)
{
    const float* x  = (const float*)d_in[0];
    const float* Wf = (const float*)d_in[1];
    const float* Uf = (const float*)d_in[2];
    const float* bf = (const float*)d_in[3];
    const float* Wb = (const float*)d_in[4];
    const float* Ub = (const float*)d_in[5];
    const float* bb = (const float*)d_in[6];
    const float* Wd = (const float*)d_in[7];
    const float* bd = (const float*)d_in[8];
    float* out = (float*)d_out;

    auto aln = [](size_t v) { return (v + 255) & ~(size_t)255; };

    // choose largest time chunk that fits in workspace
    int Tc = T_SEQ;
    bool shx = true;
    for (;;) {
        shx = (Tc == T_SEQ);
        const size_t zsz = aln((size_t)BATCH * Tc * NG * 4);
        const size_t xsz = aln((size_t)BATCH * Tc * FEAT * 2);
        const size_t need = 2 * zsz + (shx ? 2 : 4) * xsz
                          + aln(4 * WPLANE * 2) + aln(4ull * BATCH * UNITS * 4);
        if (need <= ws_size || Tc == 8) break;
        Tc >>= 1;
    }
    const int lTc = __builtin_ctz((unsigned)Tc);
    const size_t zsz = aln((size_t)BATCH * Tc * NG * 4);
    const size_t xsz = aln((size_t)BATCH * Tc * FEAT * 2);

    char* p = (char*)d_ws;
    float* zf = (float*)p; p += zsz;
    float* zb = (float*)p; p += zsz;
    unsigned short* xfh = (unsigned short*)p; p += xsz;
    unsigned short* xfl = (unsigned short*)p; p += xsz;
    unsigned short* xbh = xfh;
    unsigned short* xbl = xfl;
    if (!shx) {
        xbh = (unsigned short*)p; p += xsz;
        xbl = (unsigned short*)p; p += xsz;
    }
    unsigned short* Wt = (unsigned short*)p; p += aln(4 * WPLANE * 2);
    float* st = (float*)p;
    float* hF = st;
    float* cF = st + BATCH * UNITS;
    float* hB = st + 2 * BATCH * UNITS;
    float* cB = st + 3 * BATCH * UNITS;

    prep_w<<<dim3(WPLANE / 256, 2), 256, 0, stream>>>(Wf, Wb, Wt);

    const int n4  = BATCH * Tc * 32;          // float4 groups per x window
    const int nMT = BATCH * Tc / 32;          // 32-row M-tiles
    const int NBLK = (nMT < 512) ? nMT : 512;
    const int mpb = nMT / NBLK;
    const int nc  = T_SEQ / Tc;

    for (int c = 0; c < nc; ++c) {
        const int t0f = c * Tc;
        const int t0b = T_SEQ - (c + 1) * Tc;
        prep_x<<<2048, 256, 0, stream>>>(x, xfh, xfl, Tc, lTc, t0f, n4);
        if (!shx)
            prep_x<<<2048, 256, 0, stream>>>(x, xbh, xbl, Tc, lTc, t0b, n4);
        proj_mfma<<<dim3(NBLK, 2), 448, 0, stream>>>(
            xfh, xfl, xbh, xbl, Wt, zf, zb, mpb, nMT);
        rec3<<<dim3(BATCH, 2), 256, 0, stream>>>(
            zf, zb, Uf, Ub, bf, bb, hF, cF, hB, cB, Tc, c == 0);
    }
    head_kernel<<<BATCH, 128, 0, stream>>>(hF, hB, Wd, bd, out);
}

// Round 7
// 944.330 us; speedup vs baseline: 1.5526x; 1.0011x over previous
//
#include <hip/hip_runtime.h>
#include <hip/hip_bf16.h>
#include <math.h>

#define T_SEQ 256
#define FEAT  128
#define UNITS 50
#define NG    200   // 4*UNITS
#define OUTD  74
#define BATCH 1024
#define NPAD  224   // 7 strips of 32
#define WPLANE (NPAD * FEAT)   // 28672 elements per Wt plane

typedef __attribute__((ext_vector_type(8)))  short bf16x8;
typedef __attribute__((ext_vector_type(16))) float f32x16;

__device__ __forceinline__ unsigned short f2bf(float f) {
    unsigned u = __float_as_uint(f);
    return (unsigned short)((u + 0x7fffu + ((u >> 16) & 1u)) >> 16);
}
__device__ __forceinline__ float bf2f(unsigned short h) {
    return __uint_as_float(((unsigned)h) << 16);
}
__device__ __forceinline__ float sigf(float x) {
    return __builtin_amdgcn_rcpf(1.f + __expf(-x));
}

// ---------------------------------------------------------------------------
// Prep: W[128][200] -> W^T hi/lo bf16 [224 cols][128 k], zero-padded cols.
// Planes: 0=F_hi 1=F_lo 2=B_hi 3=B_lo
// ---------------------------------------------------------------------------
__global__ __launch_bounds__(256) void prep_w(
    const float* __restrict__ Wf, const float* __restrict__ Wb,
    unsigned short* __restrict__ Wt)
{
    const int idx = blockIdx.x * 256 + threadIdx.x;     // < 28672
    const int dir = blockIdx.y;
    const int col = idx >> 7, k = idx & 127;
    const float* W = dir ? Wb : Wf;
    const float v = (col < NG) ? W[k * NG + col] : 0.f;
    const unsigned short hi = f2bf(v);
    const unsigned short lo = f2bf(v - bf2f(hi));
    Wt[(size_t)(dir * 2 + 0) * WPLANE + idx] = hi;
    Wt[(size_t)(dir * 2 + 1) * WPLANE + idx] = lo;
}

// ---------------------------------------------------------------------------
// Prep: window of x -> bf16 hi/lo, layout [B*Tc][128] matching proj M order.
// ---------------------------------------------------------------------------
__global__ __launch_bounds__(256) void prep_x(
    const float* __restrict__ x,
    unsigned short* __restrict__ xh, unsigned short* __restrict__ xl,
    int Tc, int lTc, int t0, int n4)
{
    const int stride = gridDim.x * blockDim.x;
    for (int e4 = blockIdx.x * blockDim.x + threadIdx.x; e4 < n4; e4 += stride) {
        const int row = e4 >> 5, k4 = e4 & 31;
        const int b = row >> lTc, ti = row & (Tc - 1);
        const float4 v = *(const float4*)(x + (((size_t)(b * T_SEQ + t0 + ti)) << 7) + (k4 << 2));
        ushort4 hi, lo;
        hi.x = f2bf(v.x); lo.x = f2bf(v.x - bf2f(hi.x));
        hi.y = f2bf(v.y); lo.y = f2bf(v.y - bf2f(hi.y));
        hi.z = f2bf(v.z); lo.z = f2bf(v.z - bf2f(hi.z));
        hi.w = f2bf(v.w); lo.w = f2bf(v.w - bf2f(hi.w));
        *(ushort4*)(xh + ((size_t)e4 << 2)) = hi;
        *(ushort4*)(xl + ((size_t)e4 << 2)) = lo;
    }
}

// ---------------------------------------------------------------------------
// Projection GEMM via bf16x3 split MFMA: z[M=B*Tc][200] = X[M][128] @ W[128][200]
// Block = 7 waves (448 thr). Wave w owns col strip [w*32, w*32+32).
// B-frags (W^T hi/lo) resident in regs; A-frags global-loaded with prefetch.
// mfma_f32_32x32x16_bf16: A lane: row=l&31, k=8*(l>>5)+j; B lane: col=l&31,
// k=8*(l>>5)+j; D lane: col=l&31, row=(r&3)+8*(r>>2)+4*(l>>5).
// ---------------------------------------------------------------------------
__global__ __launch_bounds__(448, 2) void proj_mfma(
    const unsigned short* __restrict__ xfh, const unsigned short* __restrict__ xfl,
    const unsigned short* __restrict__ xbh, const unsigned short* __restrict__ xbl,
    const unsigned short* __restrict__ Wt,
    float* __restrict__ zf, float* __restrict__ zb,
    int mpb, int nMT)
{
    const int dir = blockIdx.y;
    const unsigned short* __restrict__ Ah_p = dir ? xbh : xfh;
    const unsigned short* __restrict__ Al_p = dir ? xbl : xfl;
    float* __restrict__ z = dir ? zb : zf;
    const unsigned short* __restrict__ Wth = Wt + (size_t)(dir * 2) * WPLANE;
    const unsigned short* __restrict__ Wtl = Wth + WPLANE;

    const int l    = threadIdx.x & 63;
    const int wv   = threadIdx.x >> 6;       // 0..6 strip
    const int ln   = l & 31;
    const int half = l >> 5;
    const int col  = wv * 32 + ln;

    bf16x8 Bh[8], Bl[8];
#pragma unroll
    for (int ks = 0; ks < 8; ++ks) {
        const size_t wo = (size_t)col * 128 + ks * 16 + half * 8;
        Bh[ks] = *(const bf16x8*)(Wth + wo);
        Bl[ks] = *(const bf16x8*)(Wtl + wo);
    }
    const bool colOK = (col < NG);

    int mt = blockIdx.x * mpb;
    bf16x8 Ah[8], Al[8], Ah2[8], Al2[8];
    {
        const size_t ab = ((size_t)(mt * 32 + ln)) << 7;
#pragma unroll
        for (int ks = 0; ks < 8; ++ks) {
            Ah[ks] = *(const bf16x8*)(Ah_p + ab + ks * 16 + half * 8);
            Al[ks] = *(const bf16x8*)(Al_p + ab + ks * 16 + half * 8);
        }
    }

    for (int i = 0; i < mpb; ++i) {
        // prefetch next tile's A frags
        const int mtn = (i + 1 < mpb) ? (mt + 1) : mt;
        const size_t an = ((size_t)(mtn * 32 + ln)) << 7;
#pragma unroll
        for (int ks = 0; ks < 8; ++ks) {
            Ah2[ks] = *(const bf16x8*)(Ah_p + an + ks * 16 + half * 8);
            Al2[ks] = *(const bf16x8*)(Al_p + an + ks * 16 + half * 8);
        }

        f32x16 acc = {};
#pragma unroll
        for (int ks = 0; ks < 8; ++ks) {
            acc = __builtin_amdgcn_mfma_f32_32x32x16_bf16(Ah[ks], Bh[ks], acc, 0, 0, 0);
            acc = __builtin_amdgcn_mfma_f32_32x32x16_bf16(Ah[ks], Bl[ks], acc, 0, 0, 0);
            acc = __builtin_amdgcn_mfma_f32_32x32x16_bf16(Al[ks], Bh[ks], acc, 0, 0, 0);
        }

        if (colOK) {
            float* zp = z + (size_t)(mt * 32 + half * 4) * NG + col;
#pragma unroll
            for (int r = 0; r < 16; ++r) {
                const int row = (r & 3) + ((r >> 2) << 3);
                zp[(size_t)row * NG] = acc[r];
            }
        }
#pragma unroll
        for (int ks = 0; ks < 8; ++ks) { Ah[ks] = Ah2[ks]; Al[ks] = Al2[ks]; }
        ++mt;
    }
}

// ---------------------------------------------------------------------------
// Recurrence v3b: one 256-thread block per (batch row, dir). Lane j<200 owns
// ONE gate column: U column (50 floats) in registers. R6 post-mortem: with
// bare __launch_bounds__(256) the allocator targeted 8 waves/SIMD and capped
// VGPRs at 32 -> Ur spilled to scratch -> 2.8us/step latency-bound.
// (256, 4) budgets 128 VGPRs/wave (4 waves/SIMD, ~50% occupancy) so the
// ~100 live floats stay in registers.
// ---------------------------------------------------------------------------
__global__ __launch_bounds__(256, 4) void rec3(
    const float* __restrict__ zf, const float* __restrict__ zb,
    const float* __restrict__ Uf, const float* __restrict__ Ub,
    const float* __restrict__ bf_, const float* __restrict__ bb_,
    float* __restrict__ hF, float* __restrict__ cF,
    float* __restrict__ hB, float* __restrict__ cB,
    int Tc, int first)
{
    const int j = threadIdx.x;
    const int b = blockIdx.x, dir = blockIdx.y;
    const float* __restrict__ z    = dir ? zb : zf;
    const float* __restrict__ U    = dir ? Ub : Uf;
    const float* __restrict__ bias = dir ? bb_ : bf_;
    float* __restrict__ hS = dir ? hB : hF;
    float* __restrict__ cS = dir ? cB : cF;
    const bool act = (j < NG);
    const bool isg = (j >= 100) && (j < 150);   // g-gate columns use relu

    float Ur[50];
#pragma unroll
    for (int k = 0; k < 50; ++k) Ur[k] = act ? U[k * NG + j] : 0.f;
    const float bj = act ? bias[j] : 0.f;

    __shared__ __align__(16) float hsh[52];
    __shared__ float gsh[NG];

    float c = 0.f;
    if (j < 50) {
        c      = first ? 0.f : cS[b * 50 + j];
        hsh[j] = first ? 0.f : hS[b * 50 + j];
    }
    if (j >= 50 && j < 52) hsh[j] = 0.f;
    __syncthreads();

    const int stp = dir ? -1 : 1;
    int ti = dir ? (Tc - 1) : 0;
    const float* __restrict__ zr = z + (size_t)b * Tc * NG;

    float zc = act ? zr[(size_t)ti * NG + j] : 0.f;

    for (int tt = 0; tt < Tc; ++tt) {
        const int tin = ti + stp;
        float zn = 0.f;
        if (tt + 1 < Tc && act) zn = zr[(size_t)tin * NG + j];  // prefetch

        float a = zc + bj;
#pragma unroll
        for (int k4 = 0; k4 < 12; ++k4) {
            const float4 h4 = *(const float4*)(hsh + (k4 << 2));  // broadcast
            a = fmaf(h4.x, Ur[k4 * 4 + 0], a);
            a = fmaf(h4.y, Ur[k4 * 4 + 1], a);
            a = fmaf(h4.z, Ur[k4 * 4 + 2], a);
            a = fmaf(h4.w, Ur[k4 * 4 + 3], a);
        }
        {
            const float2 h2 = *(const float2*)(hsh + 48);
            a = fmaf(h2.x, Ur[48], a);
            a = fmaf(h2.y, Ur[49], a);
        }

        const float s = sigf(a);
        const float r = fmaxf(a, 0.f);
        if (act) gsh[j] = isg ? r : s;
        __syncthreads();

        if (j < 50) {
            const float gi = gsh[j];
            const float gf = gsh[50 + j];
            const float gg = gsh[100 + j];
            const float go = gsh[150 + j];
            c = fmaf(gf, c, gi * gg);
            hsh[j] = go * fmaxf(c, 0.f);
        }
        __syncthreads();

        zc = zn;
        ti = tin;
    }

    if (j < 50) {
        hS[b * 50 + j] = hsh[j];
        cS[b * 50 + j] = c;
    }
}

// ---------------------------------------------------------------------------
// Head: logits = [h_f, h_b] @ W_d + b_d ; softmax. One block per batch row.
// ---------------------------------------------------------------------------
__global__ __launch_bounds__(128) void head_kernel(
    const float* __restrict__ hF, const float* __restrict__ hB,
    const float* __restrict__ Wd, const float* __restrict__ bd,
    float* __restrict__ out)
{
    const int b   = blockIdx.x;
    const int tid = threadIdx.x;
    __shared__ float hsh[100];
    __shared__ float red[128];

    if (tid < 50) {
        hsh[tid]      = hF[b * 50 + tid];
        hsh[50 + tid] = hB[b * 50 + tid];
    }
    __syncthreads();

    float logit = -INFINITY;
    if (tid < OUTD) {
        float acc = bd[tid];
#pragma unroll 4
        for (int k = 0; k < 100; ++k) acc = fmaf(hsh[k], Wd[k * OUTD + tid], acc);
        logit = acc;
    }
    red[tid] = logit;
    __syncthreads();
    for (int s = 64; s > 0; s >>= 1) {
        if (tid < s) red[tid] = fmaxf(red[tid], red[tid + s]);
        __syncthreads();
    }
    const float m = red[0];
    __syncthreads();
    const float e = (tid < OUTD) ? expf(logit - m) : 0.f;
    red[tid] = e;
    __syncthreads();
    for (int s = 64; s > 0; s >>= 1) {
        if (tid < s) red[tid] += red[tid + s];
        __syncthreads();
    }
    if (tid < OUTD) out[b * OUTD + tid] = e / red[0];
}

// ---------------------------------------------------------------------------
extern "C" void kernel_launch(void* const* d_in, const int* in_sizes, int n_in,
                              void* d_out, int out_size, void* d_ws, size_t ws_size,
                              hipStream_t stream)
{
    const float* x  = (const float*)d_in[0];
    const float* Wf = (const float*)d_in[1];
    const float* Uf = (const float*)d_in[2];
    const float* bf = (const float*)d_in[3];
    const float* Wb = (const float*)d_in[4];
    const float* Ub = (const float*)d_in[5];
    const float* bb = (const float*)d_in[6];
    const float* Wd = (const float*)d_in[7];
    const float* bd = (const float*)d_in[8];
    float* out = (float*)d_out;

    auto aln = [](size_t v) { return (v + 255) & ~(size_t)255; };

    // choose largest time chunk that fits in workspace
    int Tc = T_SEQ;
    bool shx = true;
    for (;;) {
        shx = (Tc == T_SEQ);
        const size_t zsz = aln((size_t)BATCH * Tc * NG * 4);
        const size_t xsz = aln((size_t)BATCH * Tc * FEAT * 2);
        const size_t need = 2 * zsz + (shx ? 2 : 4) * xsz
                          + aln(4 * WPLANE * 2) + aln(4ull * BATCH * UNITS * 4);
        if (need <= ws_size || Tc == 8) break;
        Tc >>= 1;
    }
    const int lTc = __builtin_ctz((unsigned)Tc);
    const size_t zsz = aln((size_t)BATCH * Tc * NG * 4);
    const size_t xsz = aln((size_t)BATCH * Tc * FEAT * 2);

    char* p = (char*)d_ws;
    float* zf = (float*)p; p += zsz;
    float* zb = (float*)p; p += zsz;
    unsigned short* xfh = (unsigned short*)p; p += xsz;
    unsigned short* xfl = (unsigned short*)p; p += xsz;
    unsigned short* xbh = xfh;
    unsigned short* xbl = xfl;
    if (!shx) {
        xbh = (unsigned short*)p; p += xsz;
        xbl = (unsigned short*)p; p += xsz;
    }
    unsigned short* Wt = (unsigned short*)p; p += aln(4 * WPLANE * 2);
    float* st = (float*)p;
    float* hF = st;
    float* cF = st + BATCH * UNITS;
    float* hB = st + 2 * BATCH * UNITS;
    float* cB = st + 3 * BATCH * UNITS;

    prep_w<<<dim3(WPLANE / 256, 2), 256, 0, stream>>>(Wf, Wb, Wt);

    const int n4  = BATCH * Tc * 32;          // float4 groups per x window
    const int nMT = BATCH * Tc / 32;          // 32-row M-tiles
    const int NBLK = (nMT < 512) ? nMT : 512;
    const int mpb = nMT / NBLK;
    const int nc  = T_SEQ / Tc;

    for (int c = 0; c < nc; ++c) {
        const int t0f = c * Tc;
        const int t0b = T_SEQ - (c + 1) * Tc;
        prep_x<<<2048, 256, 0, stream>>>(x, xfh, xfl, Tc, lTc, t0f, n4);
        if (!shx)
            prep_x<<<2048, 256, 0, stream>>>(x, xbh, xbl, Tc, lTc, t0b, n4);
        proj_mfma<<<dim3(NBLK, 2), 448, 0, stream>>>(
            xfh, xfl, xbh, xbl, Wt, zf, zb, mpb, nMT);
        rec3<<<dim3(BATCH, 2), 256, 0, stream>>>(
            zf, zb, Uf, Ub, bf, bb, hF, cF, hB, cB, Tc, c == 0);
    }
    head_kernel<<<BATCH, 128, 0, stream>>>(hF, hB, Wd, bd, out);
}